// Round 25
// baseline (713.939 us; speedup 1.0000x reference)
//
#include <hip/hip_runtime.h>
#include <hip/hip_bf16.h>
#include <stdint.h>

#define Bn   16
#define Nn   4096
#define Sn   1024
#define Kn   8
#define CINn 128
#define COUTn 256

#define NFPS 16
#define NBLK 240      // 16 fps + 224 feat; <= 256 CUs at 1 block/CU => all co-resident
#define NCONS (NBLK - NFPS)
#define NTILE_CONS 2016   // c0 0..1000; fps blocks handle c0=1008,1016 themselves

typedef __attribute__((ext_vector_type(8))) short bf16x8;
typedef __attribute__((ext_vector_type(4))) float f32x4;
typedef unsigned short ushort;
typedef __attribute__((ext_vector_type(8))) unsigned short ushort8;

#define ATOM_ST_F32(p, v) __hip_atomic_store((p), (v), __ATOMIC_RELAXED, __HIP_MEMORY_SCOPE_AGENT)
#define ATOM_LD_F32(p)    __hip_atomic_load((p), __ATOMIC_RELAXED, __HIP_MEMORY_SCOPE_AGENT)
#define ATOM_ST_I32(p, v) __hip_atomic_store((p), (v), __ATOMIC_RELAXED, __HIP_MEMORY_SCOPE_AGENT)
#define ATOM_LD_I32(p)    __hip_atomic_load((p), __ATOMIC_RELAXED, __HIP_MEMORY_SCOPE_AGENT)

// Exact f32 squared distance, no FMA contraction: matches ((dx*dx+dy*dy)+dz*dz)
static __device__ __forceinline__ float sqdist(float ax, float ay, float az,
                                               float bx, float by, float bz) {
    float dx = __fsub_rn(ax, bx);
    float dy = __fsub_rn(ay, by);
    float dz = __fsub_rn(az, bz);
    return __fadd_rn(__fadd_rn(__fmul_rn(dx, dx), __fmul_rn(dy, dy)), __fmul_rn(dz, dz));
}

static __device__ __forceinline__ unsigned long long u64max(unsigned long long a,
                                                            unsigned long long b) {
    return a > b ? a : b;
}

// f32 -> bf16 bits, round-to-nearest-even (finite inputs)
static __device__ __forceinline__ ushort f2bf(float f) {
    unsigned x = __float_as_uint(f);
    unsigned r = x + 0x7FFFu + ((x >> 16) & 1u);
    return (ushort)(r >> 16);
}

// Wave-wide u64 max via DPP (VALU pipe, no LDS) — r14/r20-validated on HW.
template <int CTRL>
static __device__ __forceinline__ void dpp_max_level(int& lo, int& hi) {
    int olo = __builtin_amdgcn_update_dpp(lo, lo, CTRL, 0xF, 0xF, false);
    int ohi = __builtin_amdgcn_update_dpp(hi, hi, CTRL, 0xF, 0xF, false);
    unsigned long long o = ((unsigned long long)(unsigned)ohi << 32) | (unsigned)olo;
    unsigned long long k = ((unsigned long long)(unsigned)hi << 32) | (unsigned)lo;
    if (o > k) { lo = olo; hi = ohi; }
}

static __device__ __forceinline__ unsigned long long wave_max_u64(unsigned long long key) {
    int lo = (int)(unsigned)(key & 0xFFFFFFFFull);
    int hi = (int)(unsigned)(key >> 32);
    dpp_max_level<0x111>(lo, hi);   // row_shr:1
    dpp_max_level<0x112>(lo, hi);   // row_shr:2
    dpp_max_level<0x114>(lo, hi);   // row_shr:4
    dpp_max_level<0x118>(lo, hi);   // row_shr:8
    dpp_max_level<0x142>(lo, hi);   // row_bcast:15
    dpp_max_level<0x143>(lo, hi);   // row_bcast:31
    unsigned flo = (unsigned)__builtin_amdgcn_readlane(lo, 63);
    unsigned fhi = (unsigned)__builtin_amdgcn_readlane(hi, 63);
    return ((unsigned long long)fhi << 32) | flo;
}

// ---- Wave-local ball query (validated r10-r24 ballot logic) ----------------
static __device__ __forceinline__ void wave_ball(const float* __restrict__ base,
                                                 float cx, float cy, float cz,
                                                 int lane, int* bslot) {
    int cnt = 0;
    int idx0 = -1;
    for (int chunk = 0; chunk < Nn / 64; ++chunk) {
        const int p = chunk * 64 + lane;
        const float d2 = sqdist(base[p], base[Nn + p], base[2 * Nn + p], cx, cy, cz);
        const bool in = (d2 <= 0.04f);             // f32(0.2*0.2)
        const unsigned long long m = __ballot(in);
        if (m != 0ull) {
            if (idx0 < 0) idx0 = chunk * 64 + __builtin_ctzll(m);
            const int rank = cnt + __popcll(m & ((1ull << lane) - 1ull));
            if (in && rank < Kn)
                bslot[rank] = p;                    // ascending by construction
            cnt += __popcll(m);
            if (cnt >= Kn) break;                   // wave-uniform
        }
    }
    if (lane < Kn && lane >= cnt)                   // pad with first index
        bslot[lane] = idx0;
}

// ---- One feat tile (r20 bf16-MFMA body, validated; 512 threads) ------------
static __device__ __forceinline__ void feat_tile(
        int b, int c0, char* shm,
        const float* __restrict__ xyz, const float* __restrict__ out_xyz,
        const float* __restrict__ feat, const float* __restrict__ conv_w,
        const float* __restrict__ conv_b, const float* __restrict__ bn_g,
        const float* __restrict__ bn_b, const float* __restrict__ bn_m,
        const float* __restrict__ bn_v, float* __restrict__ out_feat,
        int tid, int wave, int lane) {
    ushort (*A_lds)[136] = (ushort(*)[136])shm;                    // 17408 B
    ushort (*Wc)[40]     = (ushort(*)[40])(shm + 17408);           // 20480 B
    int (*bidx)[Kn]      = (int(*)[Kn])(shm + 17408 + 20480);      //   256 B
    const int bs = b * Sn + c0 + wave;

    // centers via agent-scope coherent loads
    const float cx = ATOM_LD_F32(&out_xyz[(size_t)bs * 3 + 0]);
    const float cy = ATOM_LD_F32(&out_xyz[(size_t)bs * 3 + 1]);
    const float cz = ATOM_LD_F32(&out_xyz[(size_t)bs * 3 + 2]);

    const float* base = xyz + (size_t)b * 3 * Nn;
    wave_ball(base, cx, cy, cz, lane, &bidx[wave][0]);
    __syncthreads();   // bidx visible to all waves (A staging reads it)

    // stage A: row r=tid>>3 (=(c<<3)|k), f-range (tid&7)*16..+15
    const float* fb = feat + (size_t)b * CINn * Nn;
    {
        const int r = tid >> 3, fo = tid & 7;
        const int pt = bidx[r >> 3][r & 7];
        ushort us[16];
#pragma unroll
        for (int i = 0; i < 16; ++i)
            us[i] = f2bf(fb[(size_t)(fo * 16 + i) * Nn + pt]);
        *(ushort8*)&A_lds[r][fo * 16]     = *(const ushort8*)&us[0];
        *(ushort8*)&A_lds[r][fo * 16 + 8] = *(const ushort8*)&us[8];
    }

    // W chunk prefetch (ks=0): thread: o=tid>>1, f-half (tid&1)*16
    const int wo = tid >> 1, wfh = tid & 1;
    float4 stgW[4];
    {
        const float4* src = (const float4*)(conv_w + (size_t)wo * CINn + wfh * 16);
#pragma unroll
        for (int i = 0; i < 4; ++i) stgW[i] = src[i];
    }

    const int mt = wave & 3;
    const int obase = (wave >> 2) * 128;
    f32x4 acc[8];
#pragma unroll
    for (int tt = 0; tt < 8; ++tt) acc[tt] = (f32x4){0.f, 0.f, 0.f, 0.f};

    const int arow = mt * 16 + (lane & 15);
    const int kgrp = (lane >> 4) * 8;

#pragma unroll
    for (int ks = 0; ks < 4; ++ks) {
        // park W chunk (16 bf16 per thread -> 2 b128 writes)
        {
            ushort us[16];
#pragma unroll
            for (int i = 0; i < 4; ++i) {
                us[i * 4 + 0] = f2bf(stgW[i].x);
                us[i * 4 + 1] = f2bf(stgW[i].y);
                us[i * 4 + 2] = f2bf(stgW[i].z);
                us[i * 4 + 3] = f2bf(stgW[i].w);
            }
            *(ushort8*)&Wc[wo][wfh * 16]     = *(const ushort8*)&us[0];
            *(ushort8*)&Wc[wo][wfh * 16 + 8] = *(const ushort8*)&us[8];
        }
        __syncthreads();   // Wc[ks] ready (iter 0: A_lds too)
        if (ks < 3) {
            const float4* src = (const float4*)(conv_w + (size_t)wo * CINn +
                                                (ks + 1) * 32 + wfh * 16);
#pragma unroll
            for (int i = 0; i < 4; ++i) stgW[i] = src[i];
        }
        const bf16x8 a = *(const bf16x8*)&A_lds[arow][ks * 32 + kgrp];
#pragma unroll
        for (int tt = 0; tt < 8; ++tt) {
            const int o = obase + tt * 16 + (lane & 15);
            const bf16x8 bb = *(const bf16x8*)&Wc[o][kgrp];
            acc[tt] = __builtin_amdgcn_mfma_f32_16x16x32_bf16(a, bb, acc[tt], 0, 0, 0);
        }
        __syncthreads();   // compute done before Wc overwrite
    }

    // epilogue: literal bias+BN+ReLU per (k,o), then max over k.
    const int half = lane >> 4;
#pragma unroll
    for (int tt = 0; tt < 8; ++tt) {
        const int o = obase + tt * 16 + (lane & 15);
        const float bias = conv_b[o];
        const float g = bn_g[o], be = bn_b[o], mn = bn_m[o], vr = bn_v[o];
        const float inv = sqrtf(vr + 1e-5f);
        float m4 = -3.402823466e+38f;
#pragma unroll
        for (int i = 0; i < 4; ++i) {
            float z = acc[tt][i] + bias;
            float y = g * (z - mn) / inv + be;
            y = fmaxf(y, 0.0f);                 // ReLU before max, literal order
            m4 = fmaxf(m4, y);
        }
        const float mo = __shfl_xor(m4, 16);
        const float mx = fmaxf(m4, mo);
        if (half == 0)
            out_feat[(size_t)(b * Sn + c0 + mt * 2) * COUTn + o] = mx;
        else if (half == 2)
            out_feat[(size_t)(b * Sn + c0 + mt * 2 + 1) * COUTn + o] = mx;
    }
}

// ---- Fused producer-consumer kernel ----------------------------------------
// Blocks 0..15: FPS for batch b (r20 chain). Center stores + progress
// publishes on WAVE 1 (tid 64) so the vmcnt drain is off wave 0's critical
// chain; publishes every 16 steps. After the chain each fps block processes
// its own batch's last two tiles (c0=1008,1016), so consumers only ever need
// progress <= 1008 (published at s=1007, before fps ends).
// Blocks 16..239: grid-stride 2016 tiles (c0 <= 1000), 9 each.
// 84KB static LDS -> 1 block/CU; 240 <= 256 CUs => all co-resident.
__global__ __launch_bounds__(512, 2) void k_fused(
        const float* __restrict__ xyz,
        const float* __restrict__ feat,
        const float* __restrict__ conv_w,
        const float* __restrict__ conv_b,
        const float* __restrict__ bn_g,
        const float* __restrict__ bn_b,
        const float* __restrict__ bn_m,
        const float* __restrict__ bn_v,
        float* __restrict__ out_xyz,
        float* __restrict__ out_feat,
        int* __restrict__ progress) {
    __shared__ __align__(16) char shm[86016];   // 84KB -> 1 block/CU
    const int tid = threadIdx.x;
    const int bid = blockIdx.x;
    const int wave = tid >> 6, lane = tid & 63;

    if (bid < NFPS) {
        // ================= FPS role (r20 chain; stores on wave 1) ==========
        const int b = bid;
        if (tid < 256) {
            float* xs = (float*)shm;
            float* ys = xs + Nn;
            float* zs = ys + Nn;
            unsigned long long (*gbuf)[4] =
                (unsigned long long(*)[4])(shm + 3 * Nn * sizeof(float));
            const int wid = tid >> 6;
            const float* base = xyz + (size_t)b * 3 * Nn;
            for (int i = tid; i < Nn; i += 256) {
                xs[i] = base[i];
                ys[i] = base[Nn + i];
                zs[i] = base[2 * Nn + i];
            }
            __syncthreads();
            float px[16], py[16], pz[16], dist[16];
#pragma unroll
            for (int j = 0; j < 16; ++j) {
                int p = tid + j * 256;
                px[j] = xs[p]; py[j] = ys[p]; pz[j] = zs[p];
                dist[j] = 3.402823466e+38f;   // FLT_MAX
            }
            int last = 0;
            if (tid == 64) {   // wave 1 owns all center stores
                ATOM_ST_F32(&out_xyz[(size_t)(b * Sn) * 3 + 0], xs[0]);
                ATOM_ST_F32(&out_xyz[(size_t)(b * Sn) * 3 + 1], ys[0]);
                ATOM_ST_F32(&out_xyz[(size_t)(b * Sn) * 3 + 2], zs[0]);
            }
            for (int s = 1; s < Sn; ++s) {
                const float cx = xs[last], cy = ys[last], cz = zs[last];
                float mv = -1.0f; int mi = 0;
#pragma unroll
                for (int j = 0; j < 16; ++j) {
                    float d = sqdist(px[j], py[j], pz[j], cx, cy, cz);
                    float nd = fminf(dist[j], d);
                    dist[j] = nd;
                    if (nd > mv) { mv = nd; mi = tid + j * 256; }  // strict >
                }
                unsigned long long key =
                    ((unsigned long long)__float_as_uint(mv) << 32) |
                    (unsigned)(Nn - 1 - mi);
                key = wave_max_u64(key);
                if (lane == 0) gbuf[s & 1][wid] = key;
                __syncthreads();
                const ulonglong2 g0 = *(const ulonglong2*)&gbuf[s & 1][0];
                const ulonglong2 g1 = *(const ulonglong2*)&gbuf[s & 1][2];
                key = u64max(u64max(g0.x, g0.y), u64max(g1.x, g1.y));
                const int nl = Nn - 1 - (int)(unsigned)(key & 0xFFFFFFFFull);
                if (tid == 64) {   // wave 1: stores + periodic drained publish
                    ATOM_ST_F32(&out_xyz[(size_t)(b * Sn + s) * 3 + 0], xs[nl]);
                    ATOM_ST_F32(&out_xyz[(size_t)(b * Sn + s) * 3 + 1], ys[nl]);
                    ATOM_ST_F32(&out_xyz[(size_t)(b * Sn + s) * 3 + 2], zs[nl]);
                    if ((s & 15) == 15) {
                        asm volatile("s_waitcnt vmcnt(0)" ::: "memory");
                        ATOM_ST_I32(progress + b, s + 1);
                    }
                }
                last = nl;
                // double-buffered gbuf: no second barrier (validated r9-r24)
            }
        } else {
            // barrier-matching idle loop: 1 staging + 1023 step barriers
            for (int s = 0; s < Sn; ++s) __syncthreads();
        }
        // ---- fps-block tail: own batch's last two tiles (c0=1008,1016) ----
        if (tid == 64) asm volatile("s_waitcnt vmcnt(0)" ::: "memory");
        __syncthreads();   // drains visible; xs/ys/zs dead -> shm reusable
        feat_tile(b, 1008, shm, xyz, out_xyz, feat, conv_w, conv_b,
                  bn_g, bn_b, bn_m, bn_v, out_feat, tid, wave, lane);
        __syncthreads();
        feat_tile(b, 1016, shm, xyz, out_xyz, feat, conv_w, conv_b,
                  bn_g, bn_b, bn_m, bn_v, out_feat, tid, wave, lane);
        return;
    }

    // ================= consumer role: tiles with c0 <= 1000 =================
    for (int t = bid - NFPS; t < NTILE_CONS; t += NCONS) {
        const int b  = t & 15;
        const int c0 = (t >> 4) * 8;
        if (tid == 0) {
            while (ATOM_LD_I32(progress + b) < c0 + 8)
                __builtin_amdgcn_s_sleep(8);
        }
        __syncthreads();
        feat_tile(b, c0, shm, xyz, out_xyz, feat, conv_w, conv_b,
                  bn_g, bn_b, bn_m, bn_v, out_feat, tid, wave, lane);
        __syncthreads();   // LDS safe to reuse next tile
    }
}

extern "C" void kernel_launch(void* const* d_in, const int* in_sizes, int n_in,
                              void* d_out, int out_size, void* d_ws, size_t ws_size,
                              hipStream_t stream) {
    const float* xyz    = (const float*)d_in[0];
    const float* feat   = (const float*)d_in[1];
    const float* conv_w = (const float*)d_in[2];
    const float* conv_b = (const float*)d_in[3];
    const float* bn_g   = (const float*)d_in[4];
    const float* bn_b   = (const float*)d_in[5];
    const float* bn_m   = (const float*)d_in[6];
    const float* bn_v   = (const float*)d_in[7];

    float* out_xyz  = (float*)d_out;
    float* out_feat = out_xyz + (size_t)Bn * Sn * 3;

    int* progress = (int*)d_ws;   // 64 B, re-zeroed every launch (graph-captured)
    hipMemsetAsync(progress, 0, Bn * sizeof(int), stream);

    k_fused<<<dim3(NBLK), dim3(512), 0, stream>>>(xyz, feat, conv_w, conv_b,
                                                  bn_g, bn_b, bn_m, bn_v,
                                                  out_xyz, out_feat, progress);
}

// Round 26
// 693.031 us; speedup vs baseline: 1.0302x; 1.0302x over previous
//
#include <hip/hip_runtime.h>
#include <hip/hip_bf16.h>
#include <stdint.h>

#define Bn   16
#define Nn   4096
#define Sn   1024
#define Kn   8
#define CINn 128
#define COUTn 256

#define NFPS 16
#define NBLK 240      // 16 fps + 224 feat; <= 256 CUs at 1 block/CU => all co-resident

typedef __attribute__((ext_vector_type(8))) short bf16x8;
typedef __attribute__((ext_vector_type(4))) float f32x4;
typedef unsigned short ushort;
typedef __attribute__((ext_vector_type(8))) unsigned short ushort8;

#define ATOM_ST_F32(p, v) __hip_atomic_store((p), (v), __ATOMIC_RELAXED, __HIP_MEMORY_SCOPE_AGENT)
#define ATOM_LD_F32(p)    __hip_atomic_load((p), __ATOMIC_RELAXED, __HIP_MEMORY_SCOPE_AGENT)
#define ATOM_ST_I32(p, v) __hip_atomic_store((p), (v), __ATOMIC_RELAXED, __HIP_MEMORY_SCOPE_AGENT)
#define ATOM_LD_I32(p)    __hip_atomic_load((p), __ATOMIC_RELAXED, __HIP_MEMORY_SCOPE_AGENT)

// Exact f32 squared distance, no FMA contraction: matches ((dx*dx+dy*dy)+dz*dz)
static __device__ __forceinline__ float sqdist(float ax, float ay, float az,
                                               float bx, float by, float bz) {
    float dx = __fsub_rn(ax, bx);
    float dy = __fsub_rn(ay, by);
    float dz = __fsub_rn(az, bz);
    return __fadd_rn(__fadd_rn(__fmul_rn(dx, dx), __fmul_rn(dy, dy)), __fmul_rn(dz, dz));
}

static __device__ __forceinline__ unsigned long long u64max(unsigned long long a,
                                                            unsigned long long b) {
    return a > b ? a : b;
}

// f32 -> bf16 bits, round-to-nearest-even (finite inputs)
static __device__ __forceinline__ ushort f2bf(float f) {
    unsigned x = __float_as_uint(f);
    unsigned r = x + 0x7FFFu + ((x >> 16) & 1u);
    return (ushort)(r >> 16);
}

// Wave-wide u64 max via DPP (VALU pipe, no LDS) — r14/r20-validated on HW.
template <int CTRL>
static __device__ __forceinline__ void dpp_max_level(int& lo, int& hi) {
    int olo = __builtin_amdgcn_update_dpp(lo, lo, CTRL, 0xF, 0xF, false);
    int ohi = __builtin_amdgcn_update_dpp(hi, hi, CTRL, 0xF, 0xF, false);
    unsigned long long o = ((unsigned long long)(unsigned)ohi << 32) | (unsigned)olo;
    unsigned long long k = ((unsigned long long)(unsigned)hi << 32) | (unsigned)lo;
    if (o > k) { lo = olo; hi = ohi; }
}

static __device__ __forceinline__ unsigned long long wave_max_u64(unsigned long long key) {
    int lo = (int)(unsigned)(key & 0xFFFFFFFFull);
    int hi = (int)(unsigned)(key >> 32);
    dpp_max_level<0x111>(lo, hi);   // row_shr:1
    dpp_max_level<0x112>(lo, hi);   // row_shr:2
    dpp_max_level<0x114>(lo, hi);   // row_shr:4
    dpp_max_level<0x118>(lo, hi);   // row_shr:8
    dpp_max_level<0x142>(lo, hi);   // row_bcast:15
    dpp_max_level<0x143>(lo, hi);   // row_bcast:31
    unsigned flo = (unsigned)__builtin_amdgcn_readlane(lo, 63);
    unsigned fhi = (unsigned)__builtin_amdgcn_readlane(hi, 63);
    return ((unsigned long long)fhi << 32) | flo;
}

// ---- Wave-local ball query (validated r10-r25 ballot logic) ----------------
static __device__ __forceinline__ void wave_ball(const float* __restrict__ base,
                                                 float cx, float cy, float cz,
                                                 int lane, int* bslot) {
    int cnt = 0;
    int idx0 = -1;
    for (int chunk = 0; chunk < Nn / 64; ++chunk) {
        const int p = chunk * 64 + lane;
        const float d2 = sqdist(base[p], base[Nn + p], base[2 * Nn + p], cx, cy, cz);
        const bool in = (d2 <= 0.04f);             // f32(0.2*0.2)
        const unsigned long long m = __ballot(in);
        if (m != 0ull) {
            if (idx0 < 0) idx0 = chunk * 64 + __builtin_ctzll(m);
            const int rank = cnt + __popcll(m & ((1ull << lane) - 1ull));
            if (in && rank < Kn)
                bslot[rank] = p;                    // ascending by construction
            cnt += __popcll(m);
            if (cnt >= Kn) break;                   // wave-uniform
        }
    }
    if (lane < Kn && lane >= cnt)                   // pad with first index
        bslot[lane] = idx0;
}

// ---- Fused producer-consumer kernel (r24 text, measured 691us optimum) -----
// Blocks 0..15: FPS for batch b (r20 chain, 624us) — centers published via
// agent-scope atomic stores; progress[b] published every 64 steps after a
// vmcnt(0) drain (tid0). Threads 256-511 run a barrier-matching idle loop.
// Blocks 16..239: feat tiles (r20 bf16-MFMA body), grid-striding 2048 tiles;
// per tile spin on progress[b] >= c0+8, centers read via agent-scope loads.
// 84KB static LDS forces 1 block/CU: 240 blocks <= 256 CUs => all co-resident
// (capacity guarantee, no dispatch-order assumption) and fps CUs exclusive.
// Variant scorecard (this session): split kernels 707; THIS 691; wave-1
// publish + fps-tail 714. FPS chain floor 624us across six implementations.
__global__ __launch_bounds__(512, 2) void k_fused(
        const float* __restrict__ xyz,
        const float* __restrict__ feat,
        const float* __restrict__ conv_w,
        const float* __restrict__ conv_b,
        const float* __restrict__ bn_g,
        const float* __restrict__ bn_b,
        const float* __restrict__ bn_m,
        const float* __restrict__ bn_v,
        float* __restrict__ out_xyz,
        float* __restrict__ out_feat,
        int* __restrict__ progress) {
    __shared__ __align__(16) char shm[86016];   // 84KB -> 1 block/CU
    const int tid = threadIdx.x;
    const int bid = blockIdx.x;

    if (bid < NFPS) {
        // ================= FPS role (r20 kernel, validated) =================
        const int b = bid;
        if (tid >= 256) {
            // barrier-matching idle loop: 1 staging + 1023 step barriers
            for (int s = 0; s < Sn; ++s) __syncthreads();
            return;
        }
        float* xs = (float*)shm;
        float* ys = xs + Nn;
        float* zs = ys + Nn;
        unsigned long long (*gbuf)[4] =
            (unsigned long long(*)[4])(shm + 3 * Nn * sizeof(float));
        const int wid = tid >> 6, lane = tid & 63;
        const float* base = xyz + (size_t)b * 3 * Nn;
        for (int i = tid; i < Nn; i += 256) {
            xs[i] = base[i];
            ys[i] = base[Nn + i];
            zs[i] = base[2 * Nn + i];
        }
        __syncthreads();
        float px[16], py[16], pz[16], dist[16];
#pragma unroll
        for (int j = 0; j < 16; ++j) {
            int p = tid + j * 256;
            px[j] = xs[p]; py[j] = ys[p]; pz[j] = zs[p];
            dist[j] = 3.402823466e+38f;   // FLT_MAX
        }
        int last = 0;
        if (tid == 0) {
            ATOM_ST_F32(&out_xyz[(size_t)(b * Sn) * 3 + 0], xs[0]);
            ATOM_ST_F32(&out_xyz[(size_t)(b * Sn) * 3 + 1], ys[0]);
            ATOM_ST_F32(&out_xyz[(size_t)(b * Sn) * 3 + 2], zs[0]);
        }
        for (int s = 1; s < Sn; ++s) {
            const float cx = xs[last], cy = ys[last], cz = zs[last];
            float mv = -1.0f; int mi = 0;
#pragma unroll
            for (int j = 0; j < 16; ++j) {
                float d = sqdist(px[j], py[j], pz[j], cx, cy, cz);
                float nd = fminf(dist[j], d);
                dist[j] = nd;
                if (nd > mv) { mv = nd; mi = tid + j * 256; }  // strict >
            }
            unsigned long long key =
                ((unsigned long long)__float_as_uint(mv) << 32) |
                (unsigned)(Nn - 1 - mi);
            key = wave_max_u64(key);
            if (lane == 0) gbuf[s & 1][wid] = key;
            __syncthreads();
            const ulonglong2 g0 = *(const ulonglong2*)&gbuf[s & 1][0];
            const ulonglong2 g1 = *(const ulonglong2*)&gbuf[s & 1][2];
            key = u64max(u64max(g0.x, g0.y), u64max(g1.x, g1.y));
            const int nl = Nn - 1 - (int)(unsigned)(key & 0xFFFFFFFFull);
            if (tid == 0) {
                ATOM_ST_F32(&out_xyz[(size_t)(b * Sn + s) * 3 + 0], xs[nl]);
                ATOM_ST_F32(&out_xyz[(size_t)(b * Sn + s) * 3 + 1], ys[nl]);
                ATOM_ST_F32(&out_xyz[(size_t)(b * Sn + s) * 3 + 2], zs[nl]);
                if ((s & 63) == 63) {
                    // drain coherent stores, then publish (release ordering by hand)
                    asm volatile("s_waitcnt vmcnt(0)" ::: "memory");
                    ATOM_ST_I32(progress + b, s + 1);
                }
            }
            last = nl;
            // double-buffered gbuf: no second barrier (validated r9-r25)
        }
        return;
    }

    // ================= feat role (r20 kernel body, validated) ===============
    ushort (*A_lds)[136] = (ushort(*)[136])shm;                    // 17408 B
    ushort (*Wc)[40]     = (ushort(*)[40])(shm + 17408);           // 20480 B
    int (*bidx)[Kn]      = (int(*)[Kn])(shm + 17408 + 20480);      //   256 B
    const int wave = tid >> 6, lane = tid & 63;

    for (int t = bid - NFPS; t < Bn * Sn / 8; t += NBLK - NFPS) {
        const int b  = t & 15;
        const int c0 = (t >> 4) * 8;
        const int bs = b * Sn + c0 + wave;

        // wait until this tile's 8 centers are published
        if (tid == 0) {
            while (ATOM_LD_I32(progress + b) < c0 + 8)
                __builtin_amdgcn_s_sleep(8);
        }
        __syncthreads();

        // centers via agent-scope coherent loads (bypass non-coherent caches)
        const float cx = ATOM_LD_F32(&out_xyz[(size_t)bs * 3 + 0]);
        const float cy = ATOM_LD_F32(&out_xyz[(size_t)bs * 3 + 1]);
        const float cz = ATOM_LD_F32(&out_xyz[(size_t)bs * 3 + 2]);

        const float* base = xyz + (size_t)b * 3 * Nn;
        wave_ball(base, cx, cy, cz, lane, &bidx[wave][0]);
        __syncthreads();   // bidx visible to all waves (A staging reads it)

        // stage A: row r=tid>>3 (=(c<<3)|k), f-range (tid&7)*16..+15
        const float* fb = feat + (size_t)b * CINn * Nn;
        {
            const int r = tid >> 3, fo = tid & 7;
            const int pt = bidx[r >> 3][r & 7];
            ushort us[16];
#pragma unroll
            for (int i = 0; i < 16; ++i)
                us[i] = f2bf(fb[(size_t)(fo * 16 + i) * Nn + pt]);
            *(ushort8*)&A_lds[r][fo * 16]     = *(const ushort8*)&us[0];
            *(ushort8*)&A_lds[r][fo * 16 + 8] = *(const ushort8*)&us[8];
        }

        // W chunk prefetch (ks=0): thread: o=tid>>1, f-half (tid&1)*16
        const int wo = tid >> 1, wfh = tid & 1;
        float4 stgW[4];
        {
            const float4* src = (const float4*)(conv_w + (size_t)wo * CINn + wfh * 16);
#pragma unroll
            for (int i = 0; i < 4; ++i) stgW[i] = src[i];
        }

        const int mt = wave & 3;
        const int obase = (wave >> 2) * 128;
        f32x4 acc[8];
#pragma unroll
        for (int tt = 0; tt < 8; ++tt) acc[tt] = (f32x4){0.f, 0.f, 0.f, 0.f};

        const int arow = mt * 16 + (lane & 15);
        const int kgrp = (lane >> 4) * 8;

#pragma unroll
        for (int ks = 0; ks < 4; ++ks) {
            // park W chunk (16 bf16 per thread -> 2 b128 writes)
            {
                ushort us[16];
#pragma unroll
                for (int i = 0; i < 4; ++i) {
                    us[i * 4 + 0] = f2bf(stgW[i].x);
                    us[i * 4 + 1] = f2bf(stgW[i].y);
                    us[i * 4 + 2] = f2bf(stgW[i].z);
                    us[i * 4 + 3] = f2bf(stgW[i].w);
                }
                *(ushort8*)&Wc[wo][wfh * 16]     = *(const ushort8*)&us[0];
                *(ushort8*)&Wc[wo][wfh * 16 + 8] = *(const ushort8*)&us[8];
            }
            __syncthreads();   // Wc[ks] ready (iter 0: A_lds too)
            if (ks < 3) {
                const float4* src = (const float4*)(conv_w + (size_t)wo * CINn +
                                                    (ks + 1) * 32 + wfh * 16);
#pragma unroll
                for (int i = 0; i < 4; ++i) stgW[i] = src[i];
            }
            const bf16x8 a = *(const bf16x8*)&A_lds[arow][ks * 32 + kgrp];
#pragma unroll
            for (int tt = 0; tt < 8; ++tt) {
                const int o = obase + tt * 16 + (lane & 15);
                const bf16x8 bb = *(const bf16x8*)&Wc[o][kgrp];
                acc[tt] = __builtin_amdgcn_mfma_f32_16x16x32_bf16(a, bb, acc[tt], 0, 0, 0);
            }
            __syncthreads();   // compute done before Wc overwrite
        }

        // epilogue: literal bias+BN+ReLU per (k,o), then max over k.
        const int half = lane >> 4;
#pragma unroll
        for (int tt = 0; tt < 8; ++tt) {
            const int o = obase + tt * 16 + (lane & 15);
            const float bias = conv_b[o];
            const float g = bn_g[o], be = bn_b[o], mn = bn_m[o], vr = bn_v[o];
            const float inv = sqrtf(vr + 1e-5f);
            float m4 = -3.402823466e+38f;
#pragma unroll
            for (int i = 0; i < 4; ++i) {
                float z = acc[tt][i] + bias;
                float y = g * (z - mn) / inv + be;
                y = fmaxf(y, 0.0f);             // ReLU before max, literal order
                m4 = fmaxf(m4, y);
            }
            const float mo = __shfl_xor(m4, 16);
            const float mx = fmaxf(m4, mo);
            if (half == 0)
                out_feat[(size_t)(b * Sn + c0 + mt * 2) * COUTn + o] = mx;
            else if (half == 2)
                out_feat[(size_t)(b * Sn + c0 + mt * 2 + 1) * COUTn + o] = mx;
        }
    }
}

extern "C" void kernel_launch(void* const* d_in, const int* in_sizes, int n_in,
                              void* d_out, int out_size, void* d_ws, size_t ws_size,
                              hipStream_t stream) {
    const float* xyz    = (const float*)d_in[0];
    const float* feat   = (const float*)d_in[1];
    const float* conv_w = (const float*)d_in[2];
    const float* conv_b = (const float*)d_in[3];
    const float* bn_g   = (const float*)d_in[4];
    const float* bn_b   = (const float*)d_in[5];
    const float* bn_m   = (const float*)d_in[6];
    const float* bn_v   = (const float*)d_in[7];

    float* out_xyz  = (float*)d_out;
    float* out_feat = out_xyz + (size_t)Bn * Sn * 3;

    int* progress = (int*)d_ws;   // 64 B, re-zeroed every launch (graph-captured)
    hipMemsetAsync(progress, 0, Bn * sizeof(int), stream);

    k_fused<<<dim3(NBLK), dim3(512), 0, stream>>>(xyz, feat, conv_w, conv_b,
                                                  bn_g, bn_b, bn_m, bn_v,
                                                  out_xyz, out_feat, progress);
}